// Round 2
// 720.033 us; speedup vs baseline: 1.0217x; 1.0217x over previous
//
#include <hip/hip_runtime.h>
#include <stdint.h>

#define NV 4096
#define NE 8192
#define FV 128
#define FE 64
#define FOUT 128

typedef unsigned short u16;
typedef __attribute__((ext_vector_type(8))) short short8;
typedef __attribute__((ext_vector_type(4))) float f32x4;
typedef __attribute__((ext_vector_type(4))) unsigned short u16x4;

__device__ __forceinline__ u16 f2bf(float f) {
  uint32_t u = __builtin_bit_cast(uint32_t, f);
  u += 0x7fffu + ((u >> 16) & 1u);   // round-to-nearest-even
  return (u16)(u >> 16);
}
__device__ __forceinline__ float bf2f(u16 h) {
  return __builtin_bit_cast(float, (uint32_t)h << 16);
}

#define AS1(p) ((__attribute__((address_space(1))) void*)(void*)(p))
#define AS3(p) ((__attribute__((address_space(3))) void*)(p))

// ---------------------------------------------------------------- d[e] = dot(H_e[e,:], p)
__global__ __launch_bounds__(64) void k_edge_dot(const float* __restrict__ He,
                                                 const float* __restrict__ p,
                                                 float* __restrict__ d) {
  int e = blockIdx.x;
  int l = threadIdx.x;
  float v = He[e * FE + l] * p[l];
  #pragma unroll
  for (int off = 32; off > 0; off >>= 1) v += __shfl_down(v, off);
  if (l == 0) d[e] = v;
}

// --------------------------------------- Ta = bf16(T * d[col]), Tb = bf16(T)  (both [NV][NE], K-major)
__global__ __launch_bounds__(256) void k_convert(const float* __restrict__ T,
                                                 const float* __restrict__ d,
                                                 u16* __restrict__ Ta,
                                                 u16* __restrict__ Tb) {
  size_t idx = ((size_t)blockIdx.x * 256 + threadIdx.x) * 4;
  f32x4 t = *(const f32x4*)&T[idx];
  int e = (int)(idx & (NE - 1));
  f32x4 dv = *(const f32x4*)&d[e];
  u16x4 a, b;
  a.x = f2bf(t.x * dv.x); a.y = f2bf(t.y * dv.y);
  a.z = f2bf(t.z * dv.z); a.w = f2bf(t.w * dv.w);
  b.x = f2bf(t.x); b.y = f2bf(t.y); b.z = f2bf(t.z); b.w = f2bf(t.w);
  *(u16x4*)&Ta[idx] = a;
  *(u16x4*)&Tb[idx] = b;
}

// ---------------------------- HWt[n][i] = bf16( sum_f Hv[i][f] * W[f][n] )  ([FOUT][NV], K-major for gemm_out)
__global__ __launch_bounds__(128) void k_hw(const float* __restrict__ Hv,
                                            const float* __restrict__ W,
                                            u16* __restrict__ HWt) {
  __shared__ float sh[FV];
  int i = blockIdx.x;
  int n = threadIdx.x;
  sh[n] = Hv[i * FV + n];
  __syncthreads();
  float s = 0.f;
  #pragma unroll
  for (int f = 0; f < FV; ++f) s += sh[f] * W[f * FOUT + n];
  HWt[(size_t)n * NV + i] = f2bf(s);
}

// ------------------------- out[0:NV*FOUT) = bias bcast; out[NV*FOUT:) = H_e copy (2nd tuple output)
__global__ __launch_bounds__(256) void k_init_out(float* __restrict__ out,
                                                  const float* __restrict__ bias,
                                                  const float* __restrict__ He) {
  int idx = blockIdx.x * 256 + threadIdx.x;
  if (idx < NV * FOUT) out[idx] = bias[idx & (FOUT - 1)];
  else out[idx] = He[idx - NV * FOUT];
}

// ---------------------------------------------------------------------------
// Full M = Ta @ Tb^T GEMM, 256x256 tile, BK=64, 8 waves (2Mx4N), 512 threads,
// 8-phase counted-vmcnt schedule (T2 swizzle + T3/T4 + T5). Grid = 16x16 =
// 256 blocks = exactly 1 block/CU. Epilogue fuses eye-mask + adjv multiply +
// bf16 store to adjA.
//
// LDS 128 KiB: A halves [2 buf][2 khalf][256][32] at b*16384+kk*8192 (u16),
//              B halves same at +32768. Each K-half region = 16 KB.
// Swizzle: physical 16B slot = logical slot ^ ((row>>1)&3)  (applied to the
// GLOBAL source address on the write side since global_load_lds writes
// linearly; same XOR on the ds_read side). Distributes each wave b128 read
// as exactly 8 lanes per 16B bank-column (the wave64 floor).
//
// Per-iteration (2 K-tiles t=2i -> buf0, t+1 -> buf1), stage one K-half per
// phase into the region freed in the previous phase:
//   P1 cmp(b0,k0,nh0) stage (t+1).B-k1   P5 cmp(b1,k0,nh0) stage (t+2).B-k1
//   P2 cmp(b0,k0,nh1) stage (t+2).A-k0   P6 cmp(b1,k0,nh1) stage (t+3).A-k0
//   P3 cmp(b0,k1,nh0) stage (t+2).B-k0   P7 cmp(b1,k1,nh0) stage (t+3).B-k0
//   P4 cmp(b0,k1,nh1) stage (t+2).A-k1   P8 cmp(b1,k1,nh1) stage (t+3).A-k1
// vmcnt(6) at P4/P8 only (3 stages = 6 loads stay in flight) -> the oldest 8
// retired loads are exactly the next tile's 4 half-tiles. Never drains to 0.
// ---------------------------------------------------------------------------
__global__ __launch_bounds__(512, 2) void k_gemm_m(const u16* __restrict__ Ta,
                                                   const u16* __restrict__ Tb,
                                                   const float* __restrict__ adjv,
                                                   u16* __restrict__ adjA) {
  __shared__ __align__(16) u16 smem[65536];   // 128 KiB

  const int bi = blockIdx.x >> 4;
  const int bj = blockIdx.x & 15;
  const int tile_m = bi * 256;
  const int tile_n = bj * 256;
  const int tid = threadIdx.x;
  const int lane = tid & 63;
  const int wid = tid >> 6;
  const int wr = wid >> 2;          // 0..1  (M half of tile)
  const int wc = wid & 3;           // 0..3  (N quarter of tile)
  const int row16 = lane & 15;
  const int quad = lane >> 4;
  const int swz8 = (quad ^ ((row16 >> 1) & 3)) * 8;   // swizzled 16B slot (u16 units)

  // ---- staging addresses (per thread, constant over the loop)
  const int srow = tid >> 2;                                 // 0..127 (r=0 rows)
  const int sslot = (tid & 3) ^ ((tid >> 3) & 3);            // pre-swizzled source slot
  const u16* gA0 = Ta + (size_t)(tile_m + srow) * NE + sslot * 8;
  const u16* gA1 = gA0 + (size_t)128 * NE;
  const u16* gB0 = Tb + (size_t)(tile_n + srow) * NE + sslot * 8;
  const u16* gB1 = gB0 + (size_t)128 * NE;
  const int ldsO0 = (wid * 64) * 8;                          // wave-uniform LDS base (u16), rows 0..127
  const int ldsO1 = (512 + wid * 64) * 8;                    // rows 128..255

#define STG(gp0, gp1, roff, kcol)                                                                 \
  do {                                                                                            \
    __builtin_amdgcn_global_load_lds(AS1((gp0) + (kcol)), AS3(&smem[(roff) + ldsO0]), 16, 0, 0);  \
    __builtin_amdgcn_global_load_lds(AS1((gp1) + (kcol)), AS3(&smem[(roff) + ldsO1]), 16, 0, 0);  \
  } while (0)

  f32x4 acc[8][4] = {};
  short8 aF[8], bF[2];

  const int arow32 = (wr * 128 + row16) * 32 + swz8;   // + mi*512
  const int brow32 = (wc * 64 + row16) * 32 + swz8;    // + (nh*2+nn)*512

#define LDA(b, kk)                                                                \
  do { _Pragma("unroll")                                                          \
    for (int mi = 0; mi < 8; ++mi)                                                \
      aF[mi] = *(const short8*)&smem[(b)*16384 + (kk)*8192 + arow32 + mi * 512];  \
  } while (0)

#define LDB(b, kk, nh)                                                                             \
  do { _Pragma("unroll")                                                                           \
    for (int nn = 0; nn < 2; ++nn)                                                                 \
      bF[nn] = *(const short8*)&smem[32768 + (b)*16384 + (kk)*8192 + brow32 + ((nh)*2+nn) * 512];  \
  } while (0)

#define MM(nh)                                                                                              \
  do { _Pragma("unroll")                                                                                    \
    for (int mi = 0; mi < 8; ++mi) {                                                                        \
      acc[mi][(nh)*2+0] = __builtin_amdgcn_mfma_f32_16x16x32_bf16(aF[mi], bF[0], acc[mi][(nh)*2+0], 0,0,0); \
      acc[mi][(nh)*2+1] = __builtin_amdgcn_mfma_f32_16x16x32_bf16(aF[mi], bF[1], acc[mi][(nh)*2+1], 0,0,0); \
    }                                                                                                       \
  } while (0)

#define BAR()   __builtin_amdgcn_s_barrier()
#define LGKM0() do { asm volatile("s_waitcnt lgkmcnt(0)" ::: "memory"); \
                     __builtin_amdgcn_sched_barrier(0); } while (0)
#define VM6()   asm volatile("s_waitcnt vmcnt(6)" ::: "memory")
#define PRIO1() __builtin_amdgcn_s_setprio(1)
#define PRIO0() __builtin_amdgcn_s_setprio(0)

  // ---- prologue: tile0 (A-k0,B-k0,A-k1,B-k1 -> buf0), tile1 (A-k0,B-k0,A-k1 -> buf1)
  STG(gA0, gA1, 0,             0);
  STG(gB0, gB1, 32768,         0);
  STG(gA0, gA1, 8192,          32);
  STG(gB0, gB1, 32768 + 8192,  32);
  STG(gA0, gA1, 16384,         64);
  STG(gB0, gB1, 32768 + 16384, 64);
  STG(gA0, gA1, 16384 + 8192,  96);
  VM6();          // tile0 fully resident; 3 stages (tile1) remain in flight
  BAR();

  for (int it = 0; it < 64; ++it) {
    const int t = it * 2;
    const int k1 = (t + 1) * 64;                          // always < 128*64
    const int k2 = (t + 2 < 128 ? t + 2 : 127) * 64;      // clamped dummy keeps vmcnt counts uniform
    const int k3 = (t + 3 < 128 ? t + 3 : 127) * 64;

    // P1: tile t, k-half 0, n-half 0
    LDA(0, 0); LDB(0, 0, 0);
    STG(gB0, gB1, 32768 + 16384 + 8192, k1 + 32);   // (t+1).B-k1 -> buf1
    BAR(); LGKM0();
    PRIO1(); MM(0); PRIO0();
    BAR();

    // P2: k-half 0, n-half 1
    LDB(0, 0, 1);
    STG(gA0, gA1, 0, k2);                           // (t+2).A-k0 -> buf0 (freed in P1)
    BAR(); LGKM0();
    PRIO1(); MM(1); PRIO0();
    BAR();

    // P3: k-half 1, n-half 0
    LDA(0, 1); LDB(0, 1, 0);
    STG(gB0, gB1, 32768, k2);                       // (t+2).B-k0 (freed in P2)
    BAR(); LGKM0();
    PRIO1(); MM(0); PRIO0();
    BAR();

    // P4: k-half 1, n-half 1 ; counted vmcnt
    LDB(0, 1, 1);
    STG(gA0, gA1, 8192, k2 + 32);                   // (t+2).A-k1 (freed in P3)
    BAR(); LGKM0();
    PRIO1(); MM(1); PRIO0();
    VM6();                                          // tile t+1 fully resident
    BAR();

    // P5: tile t+1, k-half 0, n-half 0
    LDA(1, 0); LDB(1, 0, 0);
    STG(gB0, gB1, 32768 + 8192, k2 + 32);           // (t+2).B-k1 (freed in P4)
    BAR(); LGKM0();
    PRIO1(); MM(0); PRIO0();
    BAR();

    // P6: k-half 0, n-half 1
    LDB(1, 0, 1);
    STG(gA0, gA1, 16384, k3);                       // (t+3).A-k0 -> buf1 (freed in P5)
    BAR(); LGKM0();
    PRIO1(); MM(1); PRIO0();
    BAR();

    // P7: k-half 1, n-half 0
    LDA(1, 1); LDB(1, 1, 0);
    STG(gB0, gB1, 32768 + 16384, k3);               // (t+3).B-k0 (freed in P6)
    BAR(); LGKM0();
    PRIO1(); MM(0); PRIO0();
    BAR();

    // P8: k-half 1, n-half 1 ; counted vmcnt
    LDB(1, 1, 1);
    STG(gA0, gA1, 16384 + 8192, k3 + 32);           // (t+3).A-k1 (freed in P7)
    BAR(); LGKM0();
    PRIO1(); MM(1); PRIO0();
    VM6();                                          // tile t+2 fully resident
    BAR();
  }

  // ---- fused epilogue: eye-mask + adjv elementwise + bf16 store
  // C/D layout: col = row16, row = quad*4 + r  (dtype-independent, m89/m101)
  #pragma unroll
  for (int mi = 0; mi < 8; ++mi) {
    const int gr0 = tile_m + wr * 128 + mi * 16 + quad * 4;
    #pragma unroll
    for (int ni = 0; ni < 4; ++ni) {
      const int gc = tile_n + wc * 64 + ni * 16 + row16;
      #pragma unroll
      for (int r = 0; r < 4; ++r) {
        const int gr = gr0 + r;
        float v = acc[mi][ni][r];
        v = (gr == gc) ? 1.0f : v;                  // diag of M1 is exactly 1
        v *= adjv[(size_t)gr * NV + gc];
        adjA[(size_t)gr * NV + gc] = f2bf(v);
      }
    }
  }

#undef STG
#undef LDA
#undef LDB
#undef MM
#undef BAR
#undef LGKM0
#undef VM6
#undef PRIO1
#undef PRIO0
}

// ---------------------------------------------------------------------------
// out[i][n] += sum_k adjA[i][k] * HWt[n][k]   (K-split, fp32 atomics;
// bias was pre-initialized by k_init_out)
// ---------------------------------------------------------------------------
#define KSPLIT 16
__global__ __launch_bounds__(256) void k_gemm_out(const u16* __restrict__ A,
                                                  const u16* __restrict__ B,
                                                  float* __restrict__ out) {
  __shared__ __align__(16) u16 lA[128 * 32];
  __shared__ __align__(16) u16 lB[128 * 32];
  const int K = NV;
  const int tile_m = blockIdx.y * 128;
  const int kbeg = blockIdx.x * (K / KSPLIT);
  const int kend = kbeg + (K / KSPLIT);
  const int tid = threadIdx.x;
  const int lane = tid & 63;
  const int wave = tid >> 6;
  const int wm = (wave >> 1) * 64;
  const int wn = (wave & 1) * 64;
  const int row16 = lane & 15;
  const int quad = lane >> 4;

  f32x4 acc[4][4] = {};

  for (int k0 = kbeg; k0 < kend; k0 += 32) {
    __syncthreads();
    #pragma unroll
    for (int r = 0; r < 2; ++r) {
      const int chunk = r * 256 + wave * 64 + lane;
      const int row = chunk >> 2;
      const int cc = chunk & 3;
      const u16* ga = A + ((size_t)(tile_m + row) * K + k0 + cc * 8);
      const u16* gb = B + ((size_t)row * K + k0 + cc * 8);   // N=128: full B tile
      __builtin_amdgcn_global_load_lds(AS1(ga), AS3(&lA[(r * 256 + wave * 64) * 8]), 16, 0, 0);
      __builtin_amdgcn_global_load_lds(AS1(gb), AS3(&lB[(r * 256 + wave * 64) * 8]), 16, 0, 0);
    }
    __syncthreads();
    short8 a[4], b[4];
    #pragma unroll
    for (int mi = 0; mi < 4; ++mi)
      a[mi] = *(const short8*)&lA[(wm + mi * 16 + row16) * 32 + quad * 8];
    #pragma unroll
    for (int ni = 0; ni < 4; ++ni)
      b[ni] = *(const short8*)&lB[(wn + ni * 16 + row16) * 32 + quad * 8];
    #pragma unroll
    for (int mi = 0; mi < 4; ++mi)
      #pragma unroll
      for (int ni = 0; ni < 4; ++ni)
        acc[mi][ni] = __builtin_amdgcn_mfma_f32_16x16x32_bf16(a[mi], b[ni], acc[mi][ni], 0, 0, 0);
  }

  #pragma unroll
  for (int mi = 0; mi < 4; ++mi) {
    #pragma unroll
    for (int ni = 0; ni < 4; ++ni) {
      const int gc = wn + ni * 16 + row16;      // tile_n = 0, N = 128
      #pragma unroll
      for (int r = 0; r < 4; ++r) {
        const int gr = tile_m + wm + mi * 16 + quad * 4 + r;
        atomicAdd(&out[(size_t)gr * FOUT + gc], acc[mi][ni][r]);
      }
    }
  }
}

extern "C" void kernel_launch(void* const* d_in, const int* in_sizes, int n_in,
                              void* d_out, int out_size, void* d_ws, size_t ws_size,
                              hipStream_t stream) {
  const float* Hv   = (const float*)d_in[0];
  const float* He   = (const float*)d_in[1];
  // d_in[2] = adj_e : unused in node_layer=True path
  const float* adjv = (const float*)d_in[3];
  const float* T    = (const float*)d_in[4];
  const float* W    = (const float*)d_in[5];
  const float* p    = (const float*)d_in[6];
  const float* bias = (const float*)d_in[7];
  float* out = (float*)d_out;

  // ws layout (~162 MB):
  //   [0,32KB) d | [1MB,2MB) HWt | [2MB,66MB) Ta | [66MB,130MB) Tb
  //   [130MB,162MB) adjA
  char* ws = (char*)d_ws;
  float* dvec = (float*)ws;
  u16* HWt  = (u16*)(ws + ((size_t)1 << 20));
  u16* Ta   = (u16*)(ws + ((size_t)2 << 20));
  u16* Tb   = (u16*)(ws + ((size_t)2 << 20) + ((size_t)64 << 20));
  u16* adjA = (u16*)(ws + ((size_t)2 << 20) + ((size_t)128 << 20));

  k_edge_dot<<<NE, 64, 0, stream>>>(He, p, dvec);
  k_convert<<<(NV * NE) / (256 * 4), 256, 0, stream>>>(T, dvec, Ta, Tb);
  k_hw<<<NV, 128, 0, stream>>>(Hv, W, HWt);
  k_init_out<<<(NV * FOUT + NE * FE) / 256, 256, 0, stream>>>(out, bias, He);
  k_gemm_m<<<256, 512, 0, stream>>>(Ta, Tb, adjv, adjA);
  k_gemm_out<<<dim3(KSPLIT, NV / 128), 256, 0, stream>>>(adjA, HWt, out);
}

// Round 3
// 688.933 us; speedup vs baseline: 1.0678x; 1.0451x over previous
//
#include <hip/hip_runtime.h>
#include <stdint.h>

#define NV 4096
#define NE 8192
#define FV 128
#define FE 64
#define FOUT 128

typedef unsigned short u16;
typedef __attribute__((ext_vector_type(8))) short short8;
typedef __attribute__((ext_vector_type(4))) float f32x4;
typedef __attribute__((ext_vector_type(4))) unsigned short u16x4;

__device__ __forceinline__ u16 f2bf(float f) {
  uint32_t u = __builtin_bit_cast(uint32_t, f);
  u += 0x7fffu + ((u >> 16) & 1u);   // round-to-nearest-even
  return (u16)(u >> 16);
}
__device__ __forceinline__ float bf2f(u16 h) {
  return __builtin_bit_cast(float, (uint32_t)h << 16);
}

#define AS1(p) ((__attribute__((address_space(1))) void*)(void*)(p))
#define AS3(p) ((__attribute__((address_space(3))) void*)(p))

// ------------------------------------------- d[e] = dot(H_e[e,:], p)  (grid-stride waves)
__global__ __launch_bounds__(256) void k_edge_dot(const float* __restrict__ He,
                                                  const float* __restrict__ p,
                                                  float* __restrict__ d) {
  const int lane = threadIdx.x & 63;
  const int gw = blockIdx.x * 4 + (threadIdx.x >> 6);
  const float pv = p[lane];
  for (int e = gw; e < NE; e += 512) {
    float v = He[(size_t)e * FE + lane] * pv;
    #pragma unroll
    for (int off = 32; off > 0; off >>= 1) v += __shfl_down(v, off);
    if (lane == 0) d[e] = v;
  }
}

// --------------------------- Ta = bf16(T * d[col]), Tb = bf16(T)  (8 elems/thread, 16B stores)
__global__ __launch_bounds__(256) void k_convert(const float* __restrict__ T,
                                                 const float* __restrict__ d,
                                                 u16* __restrict__ Ta,
                                                 u16* __restrict__ Tb) {
  size_t idx = ((size_t)blockIdx.x * 256 + threadIdx.x) * 8;
  f32x4 t0 = *(const f32x4*)&T[idx];
  f32x4 t1 = *(const f32x4*)&T[idx + 4];
  int e = (int)(idx & (NE - 1));
  f32x4 d0 = *(const f32x4*)&d[e];
  f32x4 d1 = *(const f32x4*)&d[e + 4];
  short8 a, b;
  a[0] = (short)f2bf(t0.x * d0.x); a[1] = (short)f2bf(t0.y * d0.y);
  a[2] = (short)f2bf(t0.z * d0.z); a[3] = (short)f2bf(t0.w * d0.w);
  a[4] = (short)f2bf(t1.x * d1.x); a[5] = (short)f2bf(t1.y * d1.y);
  a[6] = (short)f2bf(t1.z * d1.z); a[7] = (short)f2bf(t1.w * d1.w);
  b[0] = (short)f2bf(t0.x); b[1] = (short)f2bf(t0.y);
  b[2] = (short)f2bf(t0.z); b[3] = (short)f2bf(t0.w);
  b[4] = (short)f2bf(t1.x); b[5] = (short)f2bf(t1.y);
  b[6] = (short)f2bf(t1.z); b[7] = (short)f2bf(t1.w);
  *(short8*)&Ta[idx] = a;
  *(short8*)&Tb[idx] = b;
}

// ---------- HWt[n][i] = bf16( sum_f Hv[i][f] * W[f][n] )  — W staged in LDS, 8 rows/block
__global__ __launch_bounds__(256) void k_hw(const float* __restrict__ Hv,
                                            const float* __restrict__ W,
                                            u16* __restrict__ HWt) {
  __shared__ float sW[FV * FOUT];   // 64 KB
  __shared__ float sH[8 * FV];      // 4 KB
  const int tid = threadIdx.x;
  const int i0 = blockIdx.x * 8;
  #pragma unroll
  for (int k = 0; k < 16; ++k)
    *(f32x4*)&sW[k * 1024 + tid * 4] = *(const f32x4*)&W[k * 1024 + tid * 4];
  *(f32x4*)&sH[tid * 4] = *(const f32x4*)&Hv[(size_t)i0 * FV + tid * 4];
  __syncthreads();
  const int n = tid & 127;
  const int rh = tid >> 7;          // 0..1 -> rows rh*4 .. rh*4+3
  float acc[4] = {0.f, 0.f, 0.f, 0.f};
  #pragma unroll 4
  for (int f = 0; f < FV; ++f) {
    float wv = sW[f * FOUT + n];
    #pragma unroll
    for (int rr = 0; rr < 4; ++rr)
      acc[rr] += sH[(rh * 4 + rr) * FV + f] * wv;
  }
  #pragma unroll
  for (int rr = 0; rr < 4; ++rr)
    HWt[(size_t)n * NV + i0 + rh * 4 + rr] = f2bf(acc[rr]);
}

// ------------------------------------------- out[NV*FOUT:) = H_e copy (2nd tuple output)
__global__ __launch_bounds__(256) void k_copy_he(float* __restrict__ out,
                                                 const float* __restrict__ He) {
  size_t idx = ((size_t)blockIdx.x * 256 + threadIdx.x) * 4;
  *(f32x4*)&out[(size_t)NV * FOUT + idx] = *(const f32x4*)&He[idx];
}

// ---------------------------------------------------------------------------
// Full M = Ta @ Tb^T GEMM, 256x256 tile, BK=64, 8 waves (2Mx4N), 512 threads,
// 8-phase counted-vmcnt schedule. Grid = 256 blocks = 1/CU.
// Phase = (k-half, m-half): odd phases load aF4+bF4 (8 ds_read_b128), even
// phases aF4 only (bF reused in registers) -> balanced LDS vs MFMA.
// Consumption frees: P1->Bk0, P2->Ak0, P3->Bk1, P4->Ak1 (per buffer).
// Staging (one half-tile/phase, into the region freed one phase earlier):
//   P1 (t+1).Ak1->b1  P2 (t+2).Bk0->b0  P3 (t+2).Ak0->b0  P4 (t+2).Bk1->b0
//   P5 (t+2).Ak1->b0  P6 (t+3).Bk0->b1  P7 (t+3).Ak0->b1  P8 (t+3).Bk1->b1
// vmcnt(6) at P4 retires tile t+1 (staged <=P1); at P8 retires tile t+2
// (staged <=P5). 3 STG (6 loads) always in flight. Never drains to 0 in-loop.
// Epilogue: drain, LDS-transpose [256][260] bf16, coalesced adjv*mask store.
// ---------------------------------------------------------------------------
__global__ __launch_bounds__(512, 2) void k_gemm_m(const u16* __restrict__ Ta,
                                                   const u16* __restrict__ Tb,
                                                   const float* __restrict__ adjv,
                                                   u16* __restrict__ adjA) {
  __shared__ __align__(16) u16 smem[66560];   // 130 KB (main loop uses [0,65536))

  const int bi = blockIdx.x >> 4;
  const int bj = blockIdx.x & 15;
  const int tile_m = bi * 256;
  const int tile_n = bj * 256;
  const int tid = threadIdx.x;
  const int lane = tid & 63;
  const int wid = tid >> 6;
  const int wr = wid >> 2;          // 0..1  (M half)
  const int wc = wid & 3;           // 0..3  (N quarter)
  const int row16 = lane & 15;
  const int quad = lane >> 4;
  const int swz8 = (quad ^ ((row16 >> 1) & 3)) * 8;

  const int srow = tid >> 2;
  const int sslot = (tid & 3) ^ ((tid >> 3) & 3);
  const u16* gA0 = Ta + (size_t)(tile_m + srow) * NE + sslot * 8;
  const u16* gA1 = gA0 + (size_t)128 * NE;
  const u16* gB0 = Tb + (size_t)(tile_n + srow) * NE + sslot * 8;
  const u16* gB1 = gB0 + (size_t)128 * NE;
  const int ldsO0 = (wid * 64) * 8;
  const int ldsO1 = (512 + wid * 64) * 8;

#define STG(gp0, gp1, roff, kcol)                                                                 \
  do {                                                                                            \
    __builtin_amdgcn_global_load_lds(AS1((gp0) + (kcol)), AS3(&smem[(roff) + ldsO0]), 16, 0, 0);  \
    __builtin_amdgcn_global_load_lds(AS1((gp1) + (kcol)), AS3(&smem[(roff) + ldsO1]), 16, 0, 0);  \
  } while (0)

  f32x4 acc[8][4] = {};
  short8 aF[4], bF[4];

  const int arow32 = (wr * 128 + row16) * 32 + swz8;   // + (mh*4+m2)*512
  const int brow32 = (wc * 64 + row16) * 32 + swz8;    // + ni*512

#define LDA4(b, kk, mh)                                                                        \
  do { _Pragma("unroll")                                                                       \
    for (int m2 = 0; m2 < 4; ++m2)                                                             \
      aF[m2] = *(const short8*)&smem[(b)*16384 + (kk)*8192 + arow32 + ((mh)*4 + m2) * 512];    \
  } while (0)

#define LDB4(b, kk)                                                                            \
  do { _Pragma("unroll")                                                                       \
    for (int ni = 0; ni < 4; ++ni)                                                             \
      bF[ni] = *(const short8*)&smem[32768 + (b)*16384 + (kk)*8192 + brow32 + ni * 512];       \
  } while (0)

#define MMH(mh)                                                                                             \
  do { _Pragma("unroll")                                                                                    \
    for (int m2 = 0; m2 < 4; ++m2) { _Pragma("unroll")                                                      \
      for (int ni = 0; ni < 4; ++ni)                                                                        \
        acc[(mh)*4+m2][ni] = __builtin_amdgcn_mfma_f32_16x16x32_bf16(aF[m2], bF[ni], acc[(mh)*4+m2][ni], 0,0,0); \
    }                                                                                                       \
  } while (0)

#define BAR()   __builtin_amdgcn_s_barrier()
#define LGKM0() do { asm volatile("s_waitcnt lgkmcnt(0)" ::: "memory"); \
                     __builtin_amdgcn_sched_barrier(0); } while (0)
#define VM6()   asm volatile("s_waitcnt vmcnt(6)" ::: "memory")
#define PRIO1() __builtin_amdgcn_s_setprio(1)
#define PRIO0() __builtin_amdgcn_s_setprio(0)

  // Regions (u16 offsets): A: b0k0=0 b0k1=8192 b1k0=16384 b1k1=24576; B: +32768.
  // Prologue: tile0 all 4 halves, tile1 {Bk0, Ak0, Bk1}; P1 of it=0 adds tile1.Ak1.
  STG(gA0, gA1, 0,     0);
  STG(gB0, gB1, 32768, 0);
  STG(gA0, gA1, 8192,  32);
  STG(gB0, gB1, 40960, 32);
  STG(gB0, gB1, 49152, 64);
  STG(gA0, gA1, 16384, 64);
  STG(gB0, gB1, 57344, 96);
  VM6();          // tile0 resident; 3 STG (tile1) in flight
  BAR();

  for (int it = 0; it < 64; ++it) {
    const int t = it * 2;
    const int k1 = (t + 1) * 64;                          // always valid (<= 127*64)
    const int k2 = (t + 2 < 128 ? t + 2 : 127) * 64;      // clamped dummy at tail
    const int k3 = (t + 3 < 128 ? t + 3 : 127) * 64;

    // P1: (k0, m0) on buf0; stage (t+1).Ak1 -> b1 (freed prev-P8)
    LDB4(0, 0); LDA4(0, 0, 0);
    STG(gA0, gA1, 24576, k1 + 32);
    BAR(); LGKM0();
    PRIO1(); MMH(0); PRIO0();
    BAR();

    // P2: (k0, m1); stage (t+2).Bk0 -> b0 (freed P1)
    LDA4(0, 0, 1);
    STG(gB0, gB1, 32768, k2);
    BAR(); LGKM0();
    PRIO1(); MMH(1); PRIO0();
    BAR();

    // P3: (k1, m0); stage (t+2).Ak0 -> b0 (freed P2)
    LDB4(0, 1); LDA4(0, 1, 0);
    STG(gA0, gA1, 0, k2);
    BAR(); LGKM0();
    PRIO1(); MMH(0); PRIO0();
    BAR();

    // P4: (k1, m1); stage (t+2).Bk1 -> b0 (freed P3); counted vmcnt
    LDA4(0, 1, 1);
    STG(gB0, gB1, 40960, k2 + 32);
    BAR(); LGKM0();
    PRIO1(); MMH(1); PRIO0();
    VM6();                                          // tile t+1 resident
    BAR();

    // P5: buf1 (k0, m0); stage (t+2).Ak1 -> b0 (freed P4)
    LDB4(1, 0); LDA4(1, 0, 0);
    STG(gA0, gA1, 8192, k2 + 32);
    BAR(); LGKM0();
    PRIO1(); MMH(0); PRIO0();
    BAR();

    // P6: (k0, m1); stage (t+3).Bk0 -> b1 (freed P5)
    LDA4(1, 0, 1);
    STG(gB0, gB1, 49152, k3);
    BAR(); LGKM0();
    PRIO1(); MMH(1); PRIO0();
    BAR();

    // P7: (k1, m0); stage (t+3).Ak0 -> b1 (freed P6)
    LDB4(1, 1); LDA4(1, 1, 0);
    STG(gA0, gA1, 16384, k3);
    BAR(); LGKM0();
    PRIO1(); MMH(0); PRIO0();
    BAR();

    // P8: (k1, m1); stage (t+3).Bk1 -> b1 (freed P7); counted vmcnt
    LDA4(1, 1, 1);
    STG(gB0, gB1, 57344, k3 + 32);
    BAR(); LGKM0();
    PRIO1(); MMH(1); PRIO0();
    VM6();                                          // tile t+2 resident
    BAR();
  }

  // ---- epilogue: drain async stages, LDS-transpose, coalesced mask+store
  asm volatile("s_waitcnt vmcnt(0)" ::: "memory");
  __syncthreads();
  // scatter acc (C/D layout: col=row16, row=quad*4+r) -> bf16 LDS [256][260]
  // pad 260: row stride 130 words == 2 (mod 32) banks -> writes & reads 2-way (free)
  #pragma unroll
  for (int mi = 0; mi < 8; ++mi) {
    #pragma unroll
    for (int ni = 0; ni < 4; ++ni) {
      const int row = wr * 128 + mi * 16 + quad * 4;
      const int col = wc * 64 + ni * 16 + row16;
      #pragma unroll
      for (int r = 0; r < 4; ++r)
        smem[(row + r) * 260 + col] = f2bf(acc[mi][ni][r]);
    }
  }
  __syncthreads();
  const int ep_r = tid >> 4;           // 0..31
  const int ep_c = (tid & 15) * 4;     // 16 lanes -> 64 consecutive cols per j
  for (int pass = 0; pass < 8; ++pass) {
    const int row = pass * 32 + ep_r;
    const int gr = tile_m + row;
    const size_t gbase = (size_t)gr * NV + tile_n;
    #pragma unroll
    for (int j = 0; j < 4; ++j) {
      const int col = ep_c + j * 64;
      const int gc = tile_n + col;
      u16x4 m4 = *(const u16x4*)&smem[row * 260 + col];
      f32x4 av = *(const f32x4*)&adjv[gbase + col];
      u16x4 o;
      o.x = f2bf(((gr == gc + 0) ? 1.0f : bf2f(m4.x)) * av.x);
      o.y = f2bf(((gr == gc + 1) ? 1.0f : bf2f(m4.y)) * av.y);
      o.z = f2bf(((gr == gc + 2) ? 1.0f : bf2f(m4.z)) * av.z);
      o.w = f2bf(((gr == gc + 3) ? 1.0f : bf2f(m4.w)) * av.w);
      *(u16x4*)&adjA[gbase + col] = o;
    }
  }

#undef STG
#undef LDA4
#undef LDB4
#undef MMH
#undef BAR
#undef LGKM0
#undef VM6
#undef PRIO1
#undef PRIO0
}

// ---------------------------------------------------------------------------
// part[ks][i][n] = sum_{k in chunk ks} adjA[i][k] * HWt[n][k]   (no atomics)
// ---------------------------------------------------------------------------
#define KSPLIT 16
__global__ __launch_bounds__(256) void k_gemm_out(const u16* __restrict__ A,
                                                  const u16* __restrict__ B,
                                                  float* __restrict__ part) {
  __shared__ __align__(16) u16 lA[128 * 32];
  __shared__ __align__(16) u16 lB[128 * 32];
  const int K = NV;
  const int tile_m = blockIdx.y * 128;
  const int kbeg = blockIdx.x * (K / KSPLIT);
  const int kend = kbeg + (K / KSPLIT);
  const int tid = threadIdx.x;
  const int lane = tid & 63;
  const int wave = tid >> 6;
  const int wm = (wave >> 1) * 64;
  const int wn = (wave & 1) * 64;
  const int row16 = lane & 15;
  const int quad = lane >> 4;

  f32x4 acc[4][4] = {};

  for (int k0 = kbeg; k0 < kend; k0 += 32) {
    __syncthreads();
    #pragma unroll
    for (int r = 0; r < 2; ++r) {
      const int chunk = r * 256 + wave * 64 + lane;
      const int row = chunk >> 2;
      const int cc = chunk & 3;
      const u16* ga = A + ((size_t)(tile_m + row) * K + k0 + cc * 8);
      const u16* gb = B + ((size_t)row * K + k0 + cc * 8);   // N=128: full B tile
      __builtin_amdgcn_global_load_lds(AS1(ga), AS3(&lA[(r * 256 + wave * 64) * 8]), 16, 0, 0);
      __builtin_amdgcn_global_load_lds(AS1(gb), AS3(&lB[(r * 256 + wave * 64) * 8]), 16, 0, 0);
    }
    __syncthreads();
    short8 a[4], b[4];
    #pragma unroll
    for (int mi = 0; mi < 4; ++mi)
      a[mi] = *(const short8*)&lA[(wm + mi * 16 + row16) * 32 + quad * 8];
    #pragma unroll
    for (int ni = 0; ni < 4; ++ni)
      b[ni] = *(const short8*)&lB[(wn + ni * 16 + row16) * 32 + quad * 8];
    #pragma unroll
    for (int mi = 0; mi < 4; ++mi)
      #pragma unroll
      for (int ni = 0; ni < 4; ++ni)
        acc[mi][ni] = __builtin_amdgcn_mfma_f32_16x16x32_bf16(a[mi], b[ni], acc[mi][ni], 0, 0, 0);
  }

  float* pdst = part + (size_t)blockIdx.x * NV * FOUT;
  #pragma unroll
  for (int mi = 0; mi < 4; ++mi) {
    #pragma unroll
    for (int ni = 0; ni < 4; ++ni) {
      const int gc = wn + ni * 16 + row16;
      #pragma unroll
      for (int r = 0; r < 4; ++r) {
        const int gr = tile_m + wm + mi * 16 + quad * 4 + r;
        pdst[(size_t)gr * FOUT + gc] = acc[mi][ni][r];
      }
    }
  }
}

// ---------------------- out[i][n] = bias[n] + sum_ks part[ks][i][n]
__global__ __launch_bounds__(256) void k_reduce(const float* __restrict__ part,
                                                const float* __restrict__ bias,
                                                float* __restrict__ out) {
  size_t idx = ((size_t)blockIdx.x * 256 + threadIdx.x) * 4;
  f32x4 s = *(const f32x4*)&bias[idx & (FOUT - 1)];
  #pragma unroll
  for (int ks = 0; ks < KSPLIT; ++ks)
    s += *(const f32x4*)&part[(size_t)ks * NV * FOUT + idx];
  *(f32x4*)&out[idx] = s;
}

extern "C" void kernel_launch(void* const* d_in, const int* in_sizes, int n_in,
                              void* d_out, int out_size, void* d_ws, size_t ws_size,
                              hipStream_t stream) {
  const float* Hv   = (const float*)d_in[0];
  const float* He   = (const float*)d_in[1];
  // d_in[2] = adj_e : unused in node_layer=True path
  const float* adjv = (const float*)d_in[3];
  const float* T    = (const float*)d_in[4];
  const float* W    = (const float*)d_in[5];
  const float* p    = (const float*)d_in[6];
  const float* bias = (const float*)d_in[7];
  float* out = (float*)d_out;

  // ws layout (~194 MB):
  //   [0,32KB) d | [1MB,2MB) HWt | [2MB,66MB) Ta | [66MB,130MB) Tb
  //   [130MB,162MB) adjA | [162MB,194MB) part (16 x NV x FOUT f32)
  char* ws = (char*)d_ws;
  float* dvec = (float*)ws;
  u16* HWt    = (u16*)(ws + ((size_t)1 << 20));
  u16* Ta     = (u16*)(ws + ((size_t)2 << 20));
  u16* Tb     = (u16*)(ws + ((size_t)2 << 20) + ((size_t)64 << 20));
  u16* adjA   = (u16*)(ws + ((size_t)2 << 20) + ((size_t)128 << 20));
  float* part = (float*)(ws + ((size_t)2 << 20) + ((size_t)160 << 20));

  k_edge_dot<<<128, 256, 0, stream>>>(He, p, dvec);
  k_convert<<<(NV * NE) / (256 * 8), 256, 0, stream>>>(T, dvec, Ta, Tb);
  k_hw<<<NV / 8, 256, 0, stream>>>(Hv, W, HWt);
  k_copy_he<<<(NE * FE) / (256 * 4), 256, 0, stream>>>(out, He);
  k_gemm_m<<<256, 512, 0, stream>>>(Ta, Tb, adjv, adjA);
  k_gemm_out<<<dim3(KSPLIT, NV / 128), 256, 0, stream>>>(adjA, HWt, part);
  k_reduce<<<(NV * FOUT) / (256 * 4), 256, 0, stream>>>(part, bias, out);
}

// Round 4
// 674.701 us; speedup vs baseline: 1.0904x; 1.0211x over previous
//
#include <hip/hip_runtime.h>
#include <stdint.h>

#define NV 4096
#define NE 8192
#define FV 128
#define FE 64
#define FOUT 128

typedef unsigned short u16;
typedef __attribute__((ext_vector_type(8))) short short8;
typedef __attribute__((ext_vector_type(4))) float f32x4;
typedef __attribute__((ext_vector_type(4))) unsigned short u16x4;

__device__ __forceinline__ u16 f2bf(float f) {
  uint32_t u = __builtin_bit_cast(uint32_t, f);
  u += 0x7fffu + ((u >> 16) & 1u);   // round-to-nearest-even
  return (u16)(u >> 16);
}
__device__ __forceinline__ float bf2f(u16 h) {
  return __builtin_bit_cast(float, (uint32_t)h << 16);
}

#define AS1(p) ((__attribute__((address_space(1))) void*)(void*)(p))
#define AS3(p) ((__attribute__((address_space(3))) void*)(p))

// ------------------- d[e] = dot(H_e[e,:], p)  + fused H_e copy to out tuple slot 2
__global__ __launch_bounds__(256) void k_edge_dot(const float* __restrict__ He,
                                                  const float* __restrict__ p,
                                                  float* __restrict__ d,
                                                  float* __restrict__ out) {
  const int lane = threadIdx.x & 63;
  const int gw = blockIdx.x * 4 + (threadIdx.x >> 6);
  const float pv = p[lane];
  for (int e = gw; e < NE; e += 512) {
    float h = He[(size_t)e * FE + lane];
    out[(size_t)NV * FOUT + (size_t)e * FE + lane] = h;   // He copy (coalesced)
    float v = h * pv;
    #pragma unroll
    for (int off = 32; off > 0; off >>= 1) v += __shfl_down(v, off);
    if (lane == 0) d[e] = v;
  }
}

// --------------------------- Ta = bf16(T * d[col]), Tb = bf16(T)  (8 elems/thread, 16B stores)
__global__ __launch_bounds__(256) void k_convert(const float* __restrict__ T,
                                                 const float* __restrict__ d,
                                                 u16* __restrict__ Ta,
                                                 u16* __restrict__ Tb) {
  size_t idx = ((size_t)blockIdx.x * 256 + threadIdx.x) * 8;
  f32x4 t0 = *(const f32x4*)&T[idx];
  f32x4 t1 = *(const f32x4*)&T[idx + 4];
  int e = (int)(idx & (NE - 1));
  f32x4 d0 = *(const f32x4*)&d[e];
  f32x4 d1 = *(const f32x4*)&d[e + 4];
  short8 a, b;
  a[0] = (short)f2bf(t0.x * d0.x); a[1] = (short)f2bf(t0.y * d0.y);
  a[2] = (short)f2bf(t0.z * d0.z); a[3] = (short)f2bf(t0.w * d0.w);
  a[4] = (short)f2bf(t1.x * d1.x); a[5] = (short)f2bf(t1.y * d1.y);
  a[6] = (short)f2bf(t1.z * d1.z); a[7] = (short)f2bf(t1.w * d1.w);
  b[0] = (short)f2bf(t0.x); b[1] = (short)f2bf(t0.y);
  b[2] = (short)f2bf(t0.z); b[3] = (short)f2bf(t0.w);
  b[4] = (short)f2bf(t1.x); b[5] = (short)f2bf(t1.y);
  b[6] = (short)f2bf(t1.z); b[7] = (short)f2bf(t1.w);
  *(short8*)&Ta[idx] = a;
  *(short8*)&Tb[idx] = b;
}

// ---------- HWt[n][i] = bf16( sum_f Hv[i][f] * W[f][n] )  — W staged in LDS, 8 rows/block
__global__ __launch_bounds__(256) void k_hw(const float* __restrict__ Hv,
                                            const float* __restrict__ W,
                                            u16* __restrict__ HWt) {
  __shared__ float sW[FV * FOUT];   // 64 KB
  __shared__ float sH[8 * FV];      // 4 KB
  const int tid = threadIdx.x;
  const int i0 = blockIdx.x * 8;
  #pragma unroll
  for (int k = 0; k < 16; ++k)
    *(f32x4*)&sW[k * 1024 + tid * 4] = *(const f32x4*)&W[k * 1024 + tid * 4];
  *(f32x4*)&sH[tid * 4] = *(const f32x4*)&Hv[(size_t)i0 * FV + tid * 4];
  __syncthreads();
  const int n = tid & 127;
  const int rh = tid >> 7;          // 0..1 -> rows rh*4 .. rh*4+3
  float acc[4] = {0.f, 0.f, 0.f, 0.f};
  #pragma unroll 4
  for (int f = 0; f < FV; ++f) {
    float wv = sW[f * FOUT + n];
    #pragma unroll
    for (int rr = 0; rr < 4; ++rr)
      acc[rr] += sH[(rh * 4 + rr) * FV + f] * wv;
  }
  #pragma unroll
  for (int rr = 0; rr < 4; ++rr)
    HWt[(size_t)n * NV + i0 + rh * 4 + rr] = f2bf(acc[rr]);
}

// ---------------------------------------------------------------------------
// Full M = Ta @ Tb^T GEMM, 256x256 tile, BK=64, 8 waves (2Mx4N), 512 threads.
// 8-phase schedule with REGISTER-PIPELINED fragment loads: phase p issues the
// ds_reads for phase p+1 (into the alternate aX/aY, bX/bY sets), then waits
// with a COUNTED lgkmcnt (DS ops retire in-order) so phase-p fragments are
// ready while phase-(p+1) reads overlap the MFMA cluster. One barrier/phase.
//
// LDS regions (u16 offs): A: b0k0=0 b0k1=8192 b1k0=16384 b1k1=24576; B:+32768.
// STG rotation (1 half-tile/phase): P1:(t+1).Ak1  P2:(t+2).Bk0  P3:(t+2).Ak0
//   P4:(t+2).Bk1  P5:(t+2).Ak1  P6:(t+3).Bk0  P7:(t+3).Ak0  P8:(t+3).Bk1.
// Safety: STG_p targets a region whose readers fully DRAINED at phase p-1's
// counted lgkm wait (cross-wave published by the end-of-(p-1) barrier).
// vmcnt(8) gate at end of each ODD phase retires exactly the 2 oldest STGs,
// which are precisely the regions the next two phases' reads need; in-flight
// count oscillates 8..12, never drains to 0.
// Epilogue: drain, LDS-transpose [256][260] bf16, coalesced eye-mask*adjv.
// ---------------------------------------------------------------------------
__global__ __launch_bounds__(512, 2) void k_gemm_m(const u16* __restrict__ Ta,
                                                   const u16* __restrict__ Tb,
                                                   const float* __restrict__ adjv,
                                                   u16* __restrict__ adjA) {
  __shared__ __align__(16) u16 smem[66560];   // 130 KB (main loop uses [0,65536))

  const int bi = blockIdx.x >> 4;
  const int bj = blockIdx.x & 15;
  const int tile_m = bi * 256;
  const int tile_n = bj * 256;
  const int tid = threadIdx.x;
  const int lane = tid & 63;
  const int wid = tid >> 6;
  const int wr = wid >> 2;          // 0..1  (M half)
  const int wc = wid & 3;           // 0..3  (N quarter)
  const int row16 = lane & 15;
  const int quad = lane >> 4;
  const int swz8 = (quad ^ ((row16 >> 1) & 3)) * 8;

  const int srow = tid >> 2;
  const int sslot = (tid & 3) ^ ((tid >> 3) & 3);
  const u16* gA0 = Ta + (size_t)(tile_m + srow) * NE + sslot * 8;
  const u16* gA1 = gA0 + (size_t)128 * NE;
  const u16* gB0 = Tb + (size_t)(tile_n + srow) * NE + sslot * 8;
  const u16* gB1 = gB0 + (size_t)128 * NE;
  const int ldsO0 = (wid * 64) * 8;
  const int ldsO1 = (512 + wid * 64) * 8;

#define STG(gp0, gp1, roff, kcol)                                                                 \
  do {                                                                                            \
    __builtin_amdgcn_global_load_lds(AS1((gp0) + (kcol)), AS3(&smem[(roff) + ldsO0]), 16, 0, 0);  \
    __builtin_amdgcn_global_load_lds(AS1((gp1) + (kcol)), AS3(&smem[(roff) + ldsO1]), 16, 0, 0);  \
  } while (0)

  f32x4 acc[8][4] = {};
  short8 aX[4], aY[4], bX[4], bY[4];   // ping-pong fragment sets

  const int arow32 = (wr * 128 + row16) * 32 + swz8;   // + (mh*4+m2)*512
  const int brow32 = (wc * 64 + row16) * 32 + swz8;    // + ni*512

#define LDSA(b, kk, mh, DST)                                                                   \
  do { _Pragma("unroll")                                                                       \
    for (int m2 = 0; m2 < 4; ++m2)                                                             \
      DST[m2] = *(const short8*)&smem[(b)*16384 + (kk)*8192 + arow32 + ((mh)*4 + m2) * 512];   \
  } while (0)

#define LDSB(b, kk, DST)                                                                       \
  do { _Pragma("unroll")                                                                       \
    for (int ni = 0; ni < 4; ++ni)                                                             \
      DST[ni] = *(const short8*)&smem[32768 + (b)*16384 + (kk)*8192 + brow32 + ni * 512];      \
  } while (0)

#define MMP(mh, ASET, BSET)                                                                                 \
  do { _Pragma("unroll")                                                                                    \
    for (int m2 = 0; m2 < 4; ++m2) { _Pragma("unroll")                                                      \
      for (int ni = 0; ni < 4; ++ni)                                                                        \
        acc[(mh)*4+m2][ni] = __builtin_amdgcn_mfma_f32_16x16x32_bf16(ASET[m2], BSET[ni], acc[(mh)*4+m2][ni], 0,0,0); \
    }                                                                                                       \
  } while (0)

#define BARF()  do { __builtin_amdgcn_s_barrier(); asm volatile("" ::: "memory"); } while (0)
#define WAITK(k) do { asm volatile("s_waitcnt lgkmcnt(" #k ")" ::: "memory"); \
                      __builtin_amdgcn_sched_barrier(0); } while (0)
#define GATE8() asm volatile("s_waitcnt vmcnt(8)" ::: "memory")
#define PRIO1() __builtin_amdgcn_s_setprio(1)
#define PRIO0() __builtin_amdgcn_s_setprio(0)

  // ---- prologue: stage t0{Bk0,Ak0,Bk1,Ak1}, t1{Bk0,Ak0,Bk1}; gate oldest 2; prime P1 frags
  STG(gB0, gB1, 32768, 0);
  STG(gA0, gA1, 0,     0);
  STG(gB0, gB1, 40960, 32);
  STG(gA0, gA1, 8192,  32);
  STG(gB0, gB1, 49152, 64);
  STG(gA0, gA1, 16384, 64);
  STG(gB0, gB1, 57344, 96);
  asm volatile("s_waitcnt vmcnt(10)" ::: "memory");   // t0.Bk0, t0.Ak0 landed
  BARF();
  LDSB(0, 0, bX);        // B(b0,k0) for P1/P2
  LDSA(0, 0, 0, aX);     // A(b0,k0,m0) for P1

  #pragma unroll 1
  for (int it = 0; it < 64; ++it) {
    const int t = it * 2;
    const int k1 = (t + 1) * 64;
    const int k2 = (t + 2 < 128 ? t + 2 : 127) * 64;   // clamped dummy at tail
    const int k3 = (t + 3 < 128 ? t + 3 : 127) * 64;

    // P1: mfma(b0,k0,m0)[aX,bX]; read aY<-A(b0,k0,m1); STG (t+1).Ak1
    LDSA(0, 0, 1, aY);
    STG(gA0, gA1, 24576, k1 + 32);
    WAITK(4);
    PRIO1(); MMP(0, aX, bX); PRIO0();
    GATE8(); BARF();

    // P2: mfma(b0,k0,m1)[aY,bX]; read bY<-B(b0,k1), aX<-A(b0,k1,m0); STG (t+2).Bk0
    LDSB(0, 1, bY); LDSA(0, 1, 0, aX);
    STG(gB0, gB1, 32768, k2);
    WAITK(8);
    PRIO1(); MMP(1, aY, bX); PRIO0();
    BARF();

    // P3: mfma(b0,k1,m0)[aX,bY]; read aY<-A(b0,k1,m1); STG (t+2).Ak0
    LDSA(0, 1, 1, aY);
    STG(gA0, gA1, 0, k2);
    WAITK(4);
    PRIO1(); MMP(0, aX, bY); PRIO0();
    GATE8(); BARF();

    // P4: mfma(b0,k1,m1)[aY,bY]; read bX<-B(b1,k0), aX<-A(b1,k0,m0); STG (t+2).Bk1
    LDSB(1, 0, bX); LDSA(1, 0, 0, aX);
    STG(gB0, gB1, 40960, k2 + 32);
    WAITK(8);
    PRIO1(); MMP(1, aY, bY); PRIO0();
    BARF();

    // P5: mfma(b1,k0,m0)[aX,bX]; read aY<-A(b1,k0,m1); STG (t+2).Ak1
    LDSA(1, 0, 1, aY);
    STG(gA0, gA1, 8192, k2 + 32);
    WAITK(4);
    PRIO1(); MMP(0, aX, bX); PRIO0();
    GATE8(); BARF();

    // P6: mfma(b1,k0,m1)[aY,bX]; read bY<-B(b1,k1), aX<-A(b1,k1,m0); STG (t+3).Bk0
    LDSB(1, 1, bY); LDSA(1, 1, 0, aX);
    STG(gB0, gB1, 49152, k3);
    WAITK(8);
    PRIO1(); MMP(1, aY, bX); PRIO0();
    BARF();

    // P7: mfma(b1,k1,m0)[aX,bY]; read aY<-A(b1,k1,m1); STG (t+3).Ak0
    LDSA(1, 1, 1, aY);
    STG(gA0, gA1, 16384, k3);
    WAITK(4);
    PRIO1(); MMP(0, aX, bY); PRIO0();
    GATE8(); BARF();

    // P8: mfma(b1,k1,m1)[aY,bY]; read bX<-B(b0,k0)[next], aX<-A(b0,k0,m0)[next]; STG (t+3).Bk1
    LDSB(0, 0, bX); LDSA(0, 0, 0, aX);
    STG(gB0, gB1, 57344, k3 + 32);
    WAITK(8);
    PRIO1(); MMP(1, aY, bY); PRIO0();
    BARF();
  }

  // ---- epilogue: drain everything, LDS-transpose, coalesced mask+store
  asm volatile("s_waitcnt vmcnt(0) lgkmcnt(0)" ::: "memory");
  __syncthreads();
  // scatter acc (C/D layout: col=row16, row=quad*4+r) -> bf16 LDS [256][260]
  #pragma unroll
  for (int mi = 0; mi < 8; ++mi) {
    #pragma unroll
    for (int ni = 0; ni < 4; ++ni) {
      const int row = wr * 128 + mi * 16 + quad * 4;
      const int col = wc * 64 + ni * 16 + row16;
      #pragma unroll
      for (int r = 0; r < 4; ++r)
        smem[(row + r) * 260 + col] = f2bf(acc[mi][ni][r]);
    }
  }
  __syncthreads();
  const int ep_r = tid >> 4;           // 0..31
  const int ep_c = (tid & 15) * 4;     // 16 lanes -> 64 consecutive cols per j
  for (int pass = 0; pass < 8; ++pass) {
    const int row = pass * 32 + ep_r;
    const int gr = tile_m + row;
    const size_t gbase = (size_t)gr * NV + tile_n;
    #pragma unroll
    for (int j = 0; j < 4; ++j) {
      const int col = ep_c + j * 64;
      const int gc = tile_n + col;
      u16x4 m4 = *(const u16x4*)&smem[row * 260 + col];
      f32x4 av = *(const f32x4*)&adjv[gbase + col];
      u16x4 o;
      o.x = f2bf(((gr == gc + 0) ? 1.0f : bf2f(m4.x)) * av.x);
      o.y = f2bf(((gr == gc + 1) ? 1.0f : bf2f(m4.y)) * av.y);
      o.z = f2bf(((gr == gc + 2) ? 1.0f : bf2f(m4.z)) * av.z);
      o.w = f2bf(((gr == gc + 3) ? 1.0f : bf2f(m4.w)) * av.w);
      *(u16x4*)&adjA[gbase + col] = o;
    }
  }

#undef STG
#undef LDSA
#undef LDSB
#undef MMP
#undef BARF
#undef WAITK
#undef GATE8
#undef PRIO1
#undef PRIO0
}

// ---------------------------------------------------------------------------
// part[ks][i][n] = sum_{k in chunk ks} adjA[i][k] * HWt[n][k]   (no atomics)
// ---------------------------------------------------------------------------
#define KSPLIT 8
__global__ __launch_bounds__(256) void k_gemm_out(const u16* __restrict__ A,
                                                  const u16* __restrict__ B,
                                                  float* __restrict__ part) {
  __shared__ __align__(16) u16 lA[128 * 32];
  __shared__ __align__(16) u16 lB[128 * 32];
  const int K = NV;
  const int tile_m = blockIdx.y * 128;
  const int kbeg = blockIdx.x * (K / KSPLIT);
  const int kend = kbeg + (K / KSPLIT);
  const int tid = threadIdx.x;
  const int lane = tid & 63;
  const int wave = tid >> 6;
  const int wm = (wave >> 1) * 64;
  const int wn = (wave & 1) * 64;
  const int row16 = lane & 15;
  const int quad = lane >> 4;

  f32x4 acc[4][4] = {};

  for (int k0 = kbeg; k0 < kend; k0 += 32) {
    __syncthreads();
    #pragma unroll
    for (int r = 0; r < 2; ++r) {
      const int chunk = r * 256 + wave * 64 + lane;
      const int row = chunk >> 2;
      const int cc = chunk & 3;
      const u16* ga = A + ((size_t)(tile_m + row) * K + k0 + cc * 8);
      const u16* gb = B + ((size_t)row * K + k0 + cc * 8);   // N=128: full B tile
      __builtin_amdgcn_global_load_lds(AS1(ga), AS3(&lA[(r * 256 + wave * 64) * 8]), 16, 0, 0);
      __builtin_amdgcn_global_load_lds(AS1(gb), AS3(&lB[(r * 256 + wave * 64) * 8]), 16, 0, 0);
    }
    __syncthreads();
    short8 a[4], b[4];
    #pragma unroll
    for (int mi = 0; mi < 4; ++mi)
      a[mi] = *(const short8*)&lA[(wm + mi * 16 + row16) * 32 + quad * 8];
    #pragma unroll
    for (int ni = 0; ni < 4; ++ni)
      b[ni] = *(const short8*)&lB[(wn + ni * 16 + row16) * 32 + quad * 8];
    #pragma unroll
    for (int mi = 0; mi < 4; ++mi)
      #pragma unroll
      for (int ni = 0; ni < 4; ++ni)
        acc[mi][ni] = __builtin_amdgcn_mfma_f32_16x16x32_bf16(a[mi], b[ni], acc[mi][ni], 0, 0, 0);
  }

  float* pdst = part + (size_t)blockIdx.x * NV * FOUT;
  #pragma unroll
  for (int mi = 0; mi < 4; ++mi) {
    #pragma unroll
    for (int ni = 0; ni < 4; ++ni) {
      const int gc = wn + ni * 16 + row16;
      #pragma unroll
      for (int r = 0; r < 4; ++r) {
        const int gr = tile_m + wm + mi * 16 + quad * 4 + r;
        pdst[(size_t)gr * FOUT + gc] = acc[mi][ni][r];
      }
    }
  }
}

// ---------------------- out[i][n] = bias[n] + sum_ks part[ks][i][n]
__global__ __launch_bounds__(256) void k_reduce(const float* __restrict__ part,
                                                const float* __restrict__ bias,
                                                float* __restrict__ out) {
  size_t idx = ((size_t)blockIdx.x * 256 + threadIdx.x) * 4;
  f32x4 s = *(const f32x4*)&bias[idx & (FOUT - 1)];
  #pragma unroll
  for (int ks = 0; ks < KSPLIT; ++ks)
    s += *(const f32x4*)&part[(size_t)ks * NV * FOUT + idx];
  *(f32x4*)&out[idx] = s;
}

extern "C" void kernel_launch(void* const* d_in, const int* in_sizes, int n_in,
                              void* d_out, int out_size, void* d_ws, size_t ws_size,
                              hipStream_t stream) {
  const float* Hv   = (const float*)d_in[0];
  const float* He   = (const float*)d_in[1];
  // d_in[2] = adj_e : unused in node_layer=True path
  const float* adjv = (const float*)d_in[3];
  const float* T    = (const float*)d_in[4];
  const float* W    = (const float*)d_in[5];
  const float* p    = (const float*)d_in[6];
  const float* bias = (const float*)d_in[7];
  float* out = (float*)d_out;

  // ws layout (~178 MB):
  //   [0,32KB) d | [1MB,2MB) HWt | [2MB,66MB) Ta | [66MB,130MB) Tb
  //   [130MB,162MB) adjA | [162MB,178MB) part (8 x NV x FOUT f32)
  char* ws = (char*)d_ws;
  float* dvec = (float*)ws;
  u16* HWt    = (u16*)(ws + ((size_t)1 << 20));
  u16* Ta     = (u16*)(ws + ((size_t)2 << 20));
  u16* Tb     = (u16*)(ws + ((size_t)2 << 20) + ((size_t)64 << 20));
  u16* adjA   = (u16*)(ws + ((size_t)2 << 20) + ((size_t)128 << 20));
  float* part = (float*)(ws + ((size_t)2 << 20) + ((size_t)160 << 20));

  k_edge_dot<<<128, 256, 0, stream>>>(He, p, dvec, out);
  k_convert<<<(NV * NE) / (256 * 8), 256, 0, stream>>>(T, dvec, Ta, Tb);
  k_hw<<<NV / 8, 256, 0, stream>>>(Hv, W, HWt);
  k_gemm_m<<<256, 512, 0, stream>>>(Ta, Tb, adjv, adjA);
  k_gemm_out<<<dim3(KSPLIT, NV / 128), 256, 0, stream>>>(adjA, HWt, part);
  k_reduce<<<(NV * FOUT) / (256 * 4), 256, 0, stream>>>(part, bias, out);
}